// Round 10
// baseline (3032.333 us; speedup 1.0000x reference)
//
#include <hip/hip_runtime.h>
#include <math.h>
#include <stdint.h>

// ---------------- problem constants ----------------
#define TOK   512
#define EMB   768
#define QKVD  2304
#define NHEAD 12
#define HD    64
#define MLPD  3072
#define SUBA  128

// ---------------- ws layout (bytes) ----------------
#define OFF_SCAL     0ull
#define OFF_QKV      256ull
#define OFF_SCORES   (OFF_QKV    + 4718592ull)
#define OFF_CTX      (OFF_SCORES + 6291456ull)
#define OFF_H1PRE    (OFF_CTX    + 1572864ull)
#define OFF_H1       (OFF_H1PRE  + 1572864ull)
#define OFF_M1       (OFF_H1     + 1572864ull)
#define OFF_X2       (OFF_M1     + 6291456ull)
#define OFF_M2       (OFF_X2     + 6291456ull)
#define OFF_DQ1      (OFF_M2     + 1572864ull)
#define OFF_DQ2      (OFF_DQ1    + 36864ull)
#define OFF_SUMXB1   (OFF_DQ2    + 147456ull)
#define OFF_SUMXB2   (OFF_SUMXB1 + 36864ull)
#define OFF_WDEC1    (OFF_SUMXB2 + 147456ull)
#define OFF_WDEC2    (OFF_WDEC1  + 2359296ull)
#define OFF_XQT1     (OFF_WDEC2  + 2359296ull)
#define OFF_XQT2     (OFF_XQT1   + 393216ull)
#define OFF_COND1    (OFF_XQT2   + 1572864ull)
#define OFF_COND2    (OFF_COND1  + 37748736ull)
#define WS_NEEDED    (OFF_COND2  + 37748736ull)
// optional partial-cache region (exact f32 partial sums; requires huge ws — fallback otherwise)
#define OFF_PART     ((WS_NEEDED + 255ull) & ~255ull)
#define WS_BIG       (OFF_PART + 452984832ull)

// scalar slots: 0 wmax1, 1 wmax2, 2 xmax1, 3 ymax1, 4 dmax1, 5 xmax2, 6 ymax2, 7 dmax2

typedef float f32x2 __attribute__((ext_vector_type(2)));

// packed 2xf32 fma: two INDEPENDENT IEEE f32 fmas per lane (v_pk_fma_f32).
// NUMERICS LEDGER:
//  r4-r6: builtin/fmaf form, absmax 0.0078125 (bf16 floor).
//  r7: asm v_pk_fma + cond-gen fusion + Xq 2-bit re-encode together -> absmax 0.09375.
//  r8: asm fully reverted, restructure kept -> absmax STILL 0.09375  => the deviation
//      belongs to the restructure (unlocated), NOT the packed-FMA instruction.
//  r10 (this round): re-apply asm as a single isolated change. v_pk_fma_f32 is
//      architecturally two IEEE-754 RNE f32 FMAs. Prediction: absmax unchanged at
//      0.09375. If it moves, the asm is re-implicated -> revert next round.
__device__ __forceinline__ f32x2 pkfma(f32x2 a, f32x2 b, f32x2 c){
  f32x2 d;
  asm("v_pk_fma_f32 %0, %1, %2, %3" : "=v"(d) : "v"(a), "v"(b), "v"(c));
  return d;
}

// ---------------- helpers ----------------
__device__ __forceinline__ void blockMaxAtomic(double v, unsigned long long* slot, double* red){
  int tid = threadIdx.x;
  red[tid] = v; __syncthreads();
  for (int st = 128; st > 0; st >>= 1){
    if (tid < st){ double o = red[tid+st]; if (o > red[tid]) red[tid] = o; }
    __syncthreads();
  }
  if (tid == 0) atomicMax(slot, (unsigned long long)__double_as_longlong(red[0]));
}

__device__ __forceinline__ double readSlot(const unsigned long long* s){
  return __longlong_as_double((long long)(*s));
}

// ---------------- XLA CPU f32 exp (Eigen pexp_float, FMA path) ----------------
__device__ __forceinline__ float xla_exp_f32(float _x){
  float x = fminf(_x, 88.3762626647950f);
  x = fmaxf(x, -88.3762626647949f);
  float m = floorf(fmaf(x, 1.44269504088896341f, 0.5f));
  float r = fmaf(m, -0.6931471805599453f, x);
  float r2 = __fmul_rn(r, r);
  float r3 = __fmul_rn(r2, r);
  float y  = fmaf(1.9875691500e-4f, r, 1.3981999507e-3f);
  float y1 = fmaf(4.1665795894e-2f, r, 1.6666665459e-1f);
  float y2 = __fadd_rn(r, 1.0f);
  y  = fmaf(y, r, 8.3334519073e-3f);
  y1 = fmaf(y1, r, 5.0000001201e-1f);
  y  = fmaf(y, r3, y1);
  y  = fmaf(y, r2, y2);
  int mi = (int)m;
  float two_m = __uint_as_float((unsigned)((mi + 127) << 23));
  float res = __fmul_rn(y, two_m);
  return fmaxf(res, _x);
}

// ---------------- XLA CPU f32 erf (Eigen generic_fast_erf_float) ----------------
__device__ __forceinline__ float xla_erf_f32(float v){
  float x = fmaxf(fminf(v, 4.0f), -4.0f);
  float x2 = __fmul_rn(x, x);
  float p = fmaf(x2, -2.72614225801306e-10f, 2.77068142495902e-08f);
  p = fmaf(x2, p, -2.10102402082508e-06f);
  p = fmaf(x2, p, -5.69250639462346e-05f);
  p = fmaf(x2, p, -7.34990630326855e-04f);
  p = fmaf(x2, p, -2.95459980854025e-03f);
  p = fmaf(x2, p, -1.60960333262415e-02f);
  p = __fmul_rn(x, p);
  float q = fmaf(x2, -1.45660718464996e-05f, -2.13374055278905e-04f);
  q = fmaf(x2, q, -1.68282697438203e-03f);
  q = fmaf(x2, q, -7.37332916720468e-03f);
  q = fmaf(x2, q, -1.42647390514189e-02f);
  return __fdiv_rn(p, q);
}

// ---------------- threefry2x32 (JAX-exact) ----------------
__device__ __forceinline__ uint32_t rotl32(uint32_t x, int r){ return (x << r) | (x >> (32 - r)); }

__device__ __forceinline__ void threefry2x32(uint32_t k0, uint32_t k1,
                                             uint32_t x0, uint32_t x1,
                                             uint32_t& o0, uint32_t& o1){
  uint32_t ks2 = k0 ^ k1 ^ 0x1BD11BDAu;
  x0 += k0; x1 += k1;
#define TF_R(r) { x0 += x1; x1 = rotl32(x1, r); x1 ^= x0; }
  TF_R(13) TF_R(15) TF_R(26) TF_R(6)
  x0 += k1; x1 += ks2 + 1u;
  TF_R(17) TF_R(29) TF_R(16) TF_R(24)
  x0 += ks2; x1 += k0 + 2u;
  TF_R(13) TF_R(15) TF_R(26) TF_R(6)
  x0 += k0; x1 += k1 + 3u;
  TF_R(17) TF_R(29) TF_R(16) TF_R(24)
  x0 += k1; x1 += ks2 + 4u;
  TF_R(13) TF_R(15) TF_R(26) TF_R(6)
  x0 += ks2; x1 += k0 + 5u;
#undef TF_R
  o0 = x0; o1 = x1;
}

__device__ float bits_to_noise(uint32_t bits){
  uint32_t fb = (bits >> 9) | 0x3f800000u;
  float f = __uint_as_float(fb);
  f = __fadd_rn(f, -1.0f);
  const float lo = -0.99999994f;
  float u = __fadd_rn(__fmul_rn(f, 2.0f), lo);
  u = fmaxf(lo, u);
  float x  = u;
  float xx = __fmul_rn(x, x);
  float nx = -xx;
  float l1p;
  if (fabsf(nx) < 1e-4f){
    l1p = __fmul_rn(__fadd_rn(__fmul_rn(-0.5f, nx), 1.0f), nx);
  } else {
    float u1 = __fadd_rn(nx, 1.0f);
    l1p = (float)log((double)u1);
  }
  float w = -l1p;
  float p;
  if (w < 5.0f){
    w = __fadd_rn(w, -2.5f);
    p = 2.81022636e-08f;
    p = __fadd_rn(3.43273939e-07f, __fmul_rn(p, w));
    p = __fadd_rn(-3.5233877e-06f,  __fmul_rn(p, w));
    p = __fadd_rn(-4.39150654e-06f, __fmul_rn(p, w));
    p = __fadd_rn(0.00021858087f,   __fmul_rn(p, w));
    p = __fadd_rn(-0.00125372503f,  __fmul_rn(p, w));
    p = __fadd_rn(-0.00417768164f,  __fmul_rn(p, w));
    p = __fadd_rn(0.246640727f,     __fmul_rn(p, w));
    p = __fadd_rn(1.50140941f,      __fmul_rn(p, w));
  } else {
    float sw = __fsqrt_rn(w);
    w = __fadd_rn(sw, -3.0f);
    p = -0.000200214257f;
    p = __fadd_rn(0.000100950558f, __fmul_rn(p, w));
    p = __fadd_rn(0.00134934322f,  __fmul_rn(p, w));
    p = __fadd_rn(-0.00367342844f, __fmul_rn(p, w));
    p = __fadd_rn(0.00573950773f,  __fmul_rn(p, w));
    p = __fadd_rn(-0.0076224613f,  __fmul_rn(p, w));
    p = __fadd_rn(0.00943887047f,  __fmul_rn(p, w));
    p = __fadd_rn(1.00167406f,     __fmul_rn(p, w));
    p = __fadd_rn(2.83297682f,     __fmul_rn(p, w));
  }
  float ei  = __fmul_rn(p, x);
  float nrm = __fmul_rn(1.41421354f, ei);
  return __fmul_rn(0.02f, nrm);
}

// ---------------- reductions ----------------
__global__ void absmax_f32_k(const float* p, int n, unsigned long long* slot){
  __shared__ double red[256];
  double m = 0.0;
  for (int i = blockIdx.x*256 + threadIdx.x; i < n; i += gridDim.x*256){
    double v = fabs((double)p[i]); if (v > m) m = v;
  }
  blockMaxAtomic(m, slot, red);
}

// ---------------- weight preprocessing ----------------
__global__ void wdec_gen_k(const float* W, int nW, const unsigned long long* wmax_slot,
                           unsigned char* Wdec){
  int i = blockIdx.x*256 + threadIdx.x;
  if (i >= nW) return;
  float wmax = (float)readSlot(wmax_slot);
  float d = __fdiv_rn(W[i], wmax);
  d = __fadd_rn(d, 1.0f);
  d = __fmul_rn(d, 0.5f);
  d = __fmul_rn(d, 15.0f);
  Wdec[i] = (unsigned char)(int)rintf(d);
}

// cond[j], j=i*4+k: partitionable threefry (block (0,j), xor) -> noise -> conductance
__global__ void cond_gen_k(uint32_t k0, uint32_t k1, const unsigned char* Wdec,
                           unsigned int n4, float* cond){
  unsigned int j = blockIdx.x*256u + threadIdx.x;
  if (j >= n4) return;
  uint32_t o0, o1;
  threefry2x32(k0, k1, 0u, j, o0, o1);
  float nz = bits_to_noise(o0 ^ o1);
  float bit = (float)((Wdec[j >> 2] >> (j & 3)) & 1);
  cond[j] = __fmul_rn(__fadd_rn(__fmul_rn(bit, 0.9f), 0.1f), __fadd_rn(1.0f, nz));
}

// ---------------- fused row-major GEMM ----------------
#define KTILE 32
__global__ __launch_bounds__(256) void gemm8_k(const float* src, const float* w, const float* bias,
                                               const float* resid, float* out, int N, int K){
  __shared__ float xt[EMB*8];
  __shared__ float wl[256*(KTILE+1)];
  const int tid = threadIdx.x;
  const int j  = blockIdx.x*256 + tid;
  const int t0 = blockIdx.y*8;
  for (int v = tid; v < K*8; v += 256){
    int e = v >> 3, tt = v & 7;
    xt[v] = src[(size_t)(t0+tt)*K + e];
  }
  f32x2 acc[4] = {{0.f,0.f},{0.f,0.f},{0.f,0.f},{0.f,0.f}};
  const int ntile = K / KTILE;
  for (int et = 0; et < ntile; ++et){
    __syncthreads();
    for (int v = tid; v < 256*KTILE; v += 256){
      int r = v >> 5, cc = v & 31;
      wl[r*(KTILE+1) + cc] = w[(size_t)(blockIdx.x*256 + r)*K + et*KTILE + cc];
    }
    __syncthreads();
    for (int ee = 0; ee < KTILE; ++ee){
      float wv = wl[tid*(KTILE+1) + ee];
      f32x2 wv2 = {wv, wv};
      const f32x2* xp = (const f32x2*)&xt[(et*KTILE + ee)*8];
#pragma unroll
      for (int q = 0; q < 4; ++q) acc[q] = pkfma(xp[q], wv2, acc[q]);
    }
  }
  float bv = bias[j];
#pragma unroll
  for (int q = 0; q < 4; ++q){
    float a0 = __fadd_rn(acc[q].x, bv);
    float a1 = __fadd_rn(acc[q].y, bv);
    size_t ta = (size_t)(t0 + q*2), tb = ta + 1;
    if (resid){
      out[ta*N + j] = __fadd_rn(resid[ta*N + j], a0);
      out[tb*N + j] = __fadd_rn(resid[tb*N + j], a1);
    } else {
      out[ta*N + j] = a0;
      out[tb*N + j] = a1;
    }
  }
}

// ---------------- attention ----------------
__global__ __launch_bounds__(256) void attn_scores_k(const float* qkv, float* sc){
  __shared__ float kt[64][34];
  int nh = blockIdx.x;
  int n  = nh / NHEAD, h = nh % NHEAD;
  int m0 = blockIdx.y * 32;
  int l  = threadIdx.x;
  for (int v = threadIdx.x; v < 32*64; v += 256){
    int mm = v >> 6, d = v & 63;
    kt[d][mm] = qkv[(size_t)((m0+mm)*2 + n)*QKVD + EMB + h*HD + d];
  }
  __syncthreads();
  f32x2 acc[16];
#pragma unroll
  for (int i = 0; i < 16; ++i) acc[i] = {0.f,0.f};
  const float* qrow = qkv + (size_t)(l*2 + n)*QKVD + h*HD;
  for (int d = 0; d < HD; ++d){
    float qv = qrow[d];
    f32x2 q2 = {qv, qv};
    const f32x2* kp = (const f32x2*)&kt[d][0];
#pragma unroll
    for (int i = 0; i < 16; ++i) acc[i] = pkfma(q2, kp[i], acc[i]);
  }
  float* srow = sc + ((size_t)nh*256 + l)*256 + m0;
#pragma unroll
  for (int i = 0; i < 16; ++i){
    srow[2*i]   = __fdiv_rn(acc[i].x, 8.0f);
    srow[2*i+1] = __fdiv_rn(acc[i].y, 8.0f);
  }
}

__global__ void softmax_rows_k(float* sc){
  int row = blockIdx.x*256 + threadIdx.x;
  if (row >= 24*256) return;
  float* p = sc + (size_t)row*256;
  float mx = p[0];
  for (int m = 1; m < 256; ++m) mx = fmaxf(mx, p[m]);
  for (int m = 0; m < 256; ++m) p[m] = xla_exp_f32(__fsub_rn(p[m], mx));
  float s = 0.0f;
  for (int m = 0; m < 256; ++m) s = __fadd_rn(s, p[m]);
  for (int m = 0; m < 256; ++m) p[m] = __fdiv_rn(p[m], s);
}

__global__ void attn_ctx_k(const float* sc, const float* qkv, float* ctx){
  int idx = blockIdx.x*256 + threadIdx.x;
  int t = idx / 384, i2 = idx % 384;
  int i = i2*2;
  int l = t >> 1, n = t & 1, h = i >> 6;
  const float* arow = sc + ((size_t)(n*NHEAD + h)*256 + l)*256;
  f32x2 acc = {0.f,0.f};
  for (int m = 0; m < 256; ++m){
    float av = arow[m];
    f32x2 a2 = {av, av};
    f32x2 v2 = *(const f32x2*)&qkv[(size_t)(m*2 + n)*QKVD + 1536 + i];
    acc = pkfma(a2, v2, acc);
  }
  ctx[(size_t)t*EMB + i]     = acc.x;
  ctx[(size_t)t*EMB + i + 1] = acc.y;
}

__global__ void ln_rows_k(const float* in, const float* g, const float* b, float* out){
  int t = blockIdx.x*256 + threadIdx.x;
  if (t >= TOK) return;
  const float* p = in + (size_t)t*EMB;
  float s = 0.0f;
  for (int e = 0; e < EMB; ++e) s = __fadd_rn(s, p[e]);
  float mu = __fdiv_rn(s, 768.0f);
  float s2 = 0.0f;
  for (int e = 0; e < EMB; ++e){
    float d = __fsub_rn(p[e], mu);
    s2 = __fadd_rn(s2, __fmul_rn(d, d));
  }
  float var = __fdiv_rn(s2, 768.0f);
  float rs = __fdiv_rn(1.0f, __fsqrt_rn(__fadd_rn(var, 1e-5f)));
  for (int e = 0; e < EMB; ++e){
    float d = __fsub_rn(p[e], mu);
    out[(size_t)t*EMB + e] = __fadd_rn(__fmul_rn(__fmul_rn(d, rs), g[e]), b[e]);
  }
}

__global__ void final_ln_rows_k(const float* h1, const float* m2T, const float* g, const float* b, float* out){
  int t = blockIdx.x*256 + threadIdx.x;
  if (t >= TOK) return;
  const float* p = h1 + (size_t)t*EMB;
  float s = 0.0f;
  for (int e = 0; e < EMB; ++e) s = __fadd_rn(s, __fadd_rn(p[e], m2T[(size_t)e*TOK + t]));
  float mu = __fdiv_rn(s, 768.0f);
  float s2 = 0.0f;
  for (int e = 0; e < EMB; ++e){
    float d = __fsub_rn(__fadd_rn(p[e], m2T[(size_t)e*TOK + t]), mu);
    s2 = __fadd_rn(s2, __fmul_rn(d, d));
  }
  float var = __fdiv_rn(s2, 768.0f);
  float rs = __fdiv_rn(1.0f, __fsqrt_rn(__fadd_rn(var, 1e-5f)));
  for (int e = 0; e < EMB; ++e){
    float d = __fsub_rn(__fadd_rn(p[e], m2T[(size_t)e*TOK + t]), mu);
    out[(size_t)t*EMB + e] = __fadd_rn(__fmul_rn(__fmul_rn(d, rs), g[e]), b[e]);
  }
}

// ---------------- qlinear (strict f32) ----------------
// XqT2 layout: [c][t][s], one byte per s: three 2-bit signed fields (s0,s1,s2).
__device__ __forceinline__ unsigned char encode_q(int q){
  int a = q < 0 ? -q : q;
  int s0 = a & 1, s1 = (a >> 1) & 1, s2 = (a >> 2) & 1;
  if (q < 0){ s0 = -s0; s1 = -s1; s2 = -s2; }
  return (unsigned char)((s0 & 3) | ((s1 & 3) << 2) | ((s2 & 3) << 4));
}

__global__ void quantx_k(const float* val /*[t][Fin]*/, const unsigned long long* xmax_slot,
                         int Fin, unsigned char* XqT2){
  int idx = blockIdx.x*256 + threadIdx.x;
  if (idx >= TOK*Fin) return;
  int t = idx / Fin, e = idx % Fin;
  float xmax = (float)readSlot(xmax_slot);
  float u = __fmul_rn(__fdiv_rn(val[idx], xmax), 7.0f);
  XqT2[((size_t)(e >> 7)*TOK + t)*SUBA + (e & 127)] = encode_q((int)rintf(u));
}

__global__ void quantxT_k(const float* valT /*[i][t]*/, const unsigned long long* xmax_slot,
                          int Fin, unsigned char* XqT2){
  int idx = blockIdx.x*256 + threadIdx.x;
  if (idx >= TOK*Fin) return;
  int i = idx / TOK, t = idx % TOK;
  float xmax = (float)readSlot(xmax_slot);
  float u = __fmul_rn(__fdiv_rn(valT[idx], xmax), 7.0f);
  XqT2[((size_t)(i >> 7)*TOK + t)*SUBA + (i & 127)] = encode_q((int)rintf(u));
}

__global__ void sumxb_k(const unsigned char* XqT2, int NC, int* sumxb, unsigned long long* dmax_slot){
  int idx = blockIdx.x*256 + threadIdx.x;
  if (idx >= TOK*NC) return;
  int t = idx / NC, c = idx % NC;
  const unsigned char* row = XqT2 + ((size_t)c*TOK + t)*SUBA;
  int n0 = 0, n1 = 0, n2 = 0;
  for (int s = 0; s < SUBA; ++s){
    int e = (int)row[s];
    n0 += ((int)((unsigned)e << 30)) >> 30;
    n1 += ((int)((unsigned)e << 28)) >> 30;
    n2 += ((int)((unsigned)e << 26)) >> 30;
  }
  sumxb[idx*3 + 0] = n0; sumxb[idx*3 + 1] = n1; sumxb[idx*3 + 2] = n2;
  float d0 = fabsf(__fmul_rn(0.55f, (float)n0));
  float d1 = fabsf(__fmul_rn(0.55f, (float)n1));
  float d2 = fabsf(__fmul_rn(0.55f, (float)n2));
  float m = fmaxf(d0, fmaxf(d1, d2));
  atomicMax(dmax_slot, (unsigned long long)__double_as_longlong((double)m));
}

// dqT layout: [c][z][t]
__global__ void dummyq_k(const int* sumxb, int NC, const unsigned long long* dmax_slot, float* dqT){
  int idx = blockIdx.x*256 + threadIdx.x;
  if (idx >= TOK*NC*3) return;
  int t = idx / (NC*3);
  int r = idx % (NC*3);
  int c = r / 3, z = r % 3;
  float dmax = (float)readSlot(dmax_slot);
  float step = __fdiv_rn(dmax, 31.0f);
  if (!(step > 0.0f)) step = 1.0f;
  float P = __fmul_rn(0.55f, (float)sumxb[idx]);
  dqT[((size_t)c*3 + z)*TOK + t] = __fmul_rn(rintf(__fdiv_rn(P, step)), step);
}

// unified crossbar pass. P2=false: ymax (c-chunked via blockIdx.z), optionally STOREs
// exact f32 partials to `part`. P2=true: recompute pass2 (fallback path).
// Exactness: per (t,o,c,z,k) chain s=0..127 ascending; netsum per (z,k) c-ascending;
// tot z-major 12-term — identical to rounds 7-9 validated semantics.
template<int OTILE, bool P2, int CCHUNK, bool STORE>
__global__ __launch_bounds__(256) void qlin_k(const unsigned char* XqT2, const float* cond_g,
                                              const float* dqT, const float* bias,
                                              int Fin, int NC, int Fout,
                                              unsigned long long* ymax_slot,
                                              const unsigned long long* xmax_slot,
                                              const unsigned long long* wmax_slot,
                                              float* outT, float* part){
  __shared__ float4 condL4[OTILE*SUBA];
  __shared__ double red[P2 ? 1 : 256];
  const int tid = threadIdx.x;
  const int o0 = blockIdx.x*OTILE;
  const int t0 = blockIdx.y*256;
  const int t  = t0 + tid;
  const int c0 = P2 ? 0 : blockIdx.z*CCHUNK;
  const int cEnd = P2 ? NC : (c0 + CCHUNK);

  float step = 1.0f, lmax = 0.0f;
  if (P2){
    float ymax = (float)readSlot(ymax_slot);
    step = __fdiv_rn(ymax, 31.0f);
    if (!(step > 0.0f)) step = 1.0f;
  }

  f32x2 acc[OTILE][6];
  f32x2 netsum[OTILE][6];
  if (P2){
#pragma unroll
    for (int o = 0; o < OTILE; ++o)
#pragma unroll
      for (int r = 0; r < 6; ++r) netsum[o][r] = (f32x2){0.f, 0.f};
  }

  // stage cond for first c
#pragma unroll
  for (int u = 0; u < OTILE/2; ++u){
    int v = tid + u*256, o = v >> 7, r = v & 127;
    condL4[v] = ((const float4*)cond_g)[(size_t)(o0+o)*Fin + (size_t)c0*SUBA + r];
  }
  __syncthreads();

  // prime xq: first 8 dwords of first c's row
  const uint32_t* xrow = (const uint32_t*)(XqT2 + ((size_t)c0*TOK + t)*SUBA);
  uint32_t xg[8];
#pragma unroll
  for (int u = 0; u < 8; ++u) xg[u] = xrow[u];

  for (int c = c0; c < cEnd; ++c){
    const bool haveNextC = (c + 1 < cEnd);
    const uint32_t* xrow_next = haveNextC
      ? (const uint32_t*)(XqT2 + ((size_t)(c+1)*TOK + t)*SUBA) : xrow;

    // prefetch next-c cond into registers (hidden under the 128-s compute)
    float4 pf[OTILE/2];
    if (haveNextC){
#pragma unroll
      for (int u = 0; u < OTILE/2; ++u){
        int v = tid + u*256, o = v >> 7, r = v & 127;
        pf[u] = ((const float4*)cond_g)[(size_t)(o0+o)*Fin + (size_t)(c+1)*SUBA + r];
      }
    }

#pragma unroll
    for (int o = 0; o < OTILE; ++o)
#pragma unroll
      for (int r = 0; r < 6; ++r) acc[o][r] = (f32x2){0.f, 0.f};

    for (int g = 0; g < 4; ++g){            // 32 s per group; rolling prefetch incl. next c
      uint32_t xn[8];
      const uint32_t* nsrc = (g < 3) ? (xrow + (g+1)*8) : xrow_next;
#pragma unroll
      for (int u = 0; u < 8; ++u) xn[u] = nsrc[u];
      const float4* condG = condL4 + g*32;  // s-group base (float4 units)
#pragma unroll
      for (int u = 0; u < 8; ++u){
        uint32_t w = xg[u];
#pragma unroll
        for (int bb = 0; bb < 4; ++bb){
          int sl = u*4 + bb;                 // s within group (compile-time)
          int base = bb*8;
          int b0i = ((int)(w << (30 - base))) >> 30;
          int b1i = ((int)(w << (28 - base))) >> 30;
          int b2i = ((int)(w << (26 - base))) >> 30;
          float f0 = (float)b0i, f1 = (float)b1i, f2 = (float)b2i;
          f32x2 b0 = {f0, f0}, b1 = {f1, f1}, b2 = {f2, f2};
#pragma unroll
          for (int o = 0; o < OTILE; ++o){
            float4 cv = condG[o*SUBA + sl];
            f32x2 c01 = {cv.x, cv.y}, c23 = {cv.z, cv.w};
            acc[o][0] = pkfma(b0, c01, acc[o][0]);
            acc[o][1] = pkfma(b0, c23, acc[o][1]);
            acc[o][2] = pkfma(b1, c01, acc[o][2]);
            acc[o][3] = pkfma(b1, c23, acc[o][3]);
            acc[o][4] = pkfma(b2, c01, acc[o][4]);
            acc[o][5] = pkfma(b2, c23, acc[o][5]);
          }
        }
      }
#pragma unroll
      for (int u = 0; u < 8; ++u) xg[u] = xn[u];
    }
    xrow = xrow_next;

    if (P2){
      float dqv[3];
#pragma unroll
      for (int z = 0; z < 3; ++z) dqv[z] = dqT[((size_t)c*3 + z)*TOK + t];
#pragma unroll
      for (int o = 0; o < OTILE; ++o)
#pragma unroll
        for (int z = 0; z < 3; ++z)
#pragma unroll
          for (int kp = 0; kp < 2; ++kp){
            f32x2 av = acc[o][z*2 + kp];
            float pq0 = __fmul_rn(rintf(__fdiv_rn(av.x, step)), step);
            float pq1 = __fmul_rn(rintf(__fdiv_rn(av.y, step)), step);
            netsum[o][z*2+kp].x = __fadd_rn(netsum[o][z*2+kp].x, __fsub_rn(pq0, dqv[z]));
            netsum[o][z*2+kp].y = __fadd_rn(netsum[o][z*2+kp].y, __fsub_rn(pq1, dqv[z]));
          }
    } else {
      if (STORE){
        size_t base = ((size_t)c*Fout + o0)*12;
#pragma unroll
        for (int o = 0; o < OTILE; ++o)
#pragma unroll
          for (int z = 0; z < 3; ++z)
#pragma unroll
            for (int kp = 0; kp < 2; ++kp){
              part[(base + o*12 + z*4 + kp*2    )*TOK + t] = acc[o][z*2+kp].x;
              part[(base + o*12 + z*4 + kp*2 + 1)*TOK + t] = acc[o][z*2+kp].y;
            }
      }
#pragma unroll
      for (int o = 0; o < OTILE; ++o)
#pragma unroll
        for (int r = 0; r < 6; ++r){
          lmax = fmaxf(lmax, fabsf(acc[o][r].x));
          lmax = fmaxf(lmax, fabsf(acc[o][r].y));
        }
    }

    __syncthreads();
    if (haveNextC){
#pragma unroll
      for (int u = 0; u < OTILE/2; ++u)
        condL4[tid + u*256] = pf[u];
      __syncthreads();
    }
  }

  if (P2){
    float xmax = (float)readSlot(xmax_slot);
    float wmax = (float)readSlot(wmax_slot);
    float A = __fdiv_rn(xmax, 7.0f);
    float B = __fdiv_rn(__fmul_rn(2.0f, wmax), 13.5f);
#pragma unroll
    for (int o = 0; o < OTILE; ++o){
      float tot = 0.0f;
#pragma unroll
      for (int z = 0; z < 3; ++z)
#pragma unroll
        for (int k = 0; k < 4; ++k){
          f32x2 ns = netsum[o][z*2 + (k >> 1)];
          float nv = (k & 1) ? ns.y : ns.x;
          tot = __fadd_rn(tot, __fmul_rn(nv, (float)(1 << (z + k))));
        }
      float outv = __fadd_rn(__fmul_rn(__fmul_rn(tot, A), B), bias[o0+o]);
      outT[(size_t)(o0+o)*TOK + t] = outv;
    }
  } else {
    blockMaxAtomic((double)lmax, ymax_slot, red);
  }
}

// cached pass2: stream exact f32 partials (bit-identical chains to recompute pass2)
template<int OTILE>
__global__ __launch_bounds__(256) void qlin2c_k(const float* part, const float* dqT, const float* bias,
                                                int Fout, int NC,
                                                const unsigned long long* ymax_slot,
                                                const unsigned long long* xmax_slot,
                                                const unsigned long long* wmax_slot,
                                                float* outT){
  const int tid = threadIdx.x;
  const int o0 = blockIdx.x*OTILE;
  const int t  = blockIdx.y*256 + tid;
  float ymax = (float)readSlot(ymax_slot);
  float step = __fdiv_rn(ymax, 31.0f);
  if (!(step > 0.0f)) step = 1.0f;
  f32x2 netsum[OTILE][6];
#pragma unroll
  for (int o = 0; o < OTILE; ++o)
#pragma unroll
    for (int r = 0; r < 6; ++r) netsum[o][r] = (f32x2){0.f, 0.f};
  for (int c = 0; c < NC; ++c){
    float dqv[3];
#pragma unroll
    for (int z = 0; z < 3; ++z) dqv[z] = dqT[((size_t)c*3 + z)*TOK + t];
    size_t base = ((size_t)c*Fout + o0)*12;
#pragma unroll
    for (int o = 0; o < OTILE; ++o)
#pragma unroll
      for (int z = 0; z < 3; ++z)
#pragma unroll
        for (int kp = 0; kp < 2; ++kp){
          float p0 = part[(base + o*12 + z*4 + kp*2    )*TOK + t];
          float p1 = part[(base + o*12 + z*4 + kp*2 + 1)*TOK + t];
          float pq0 = __fmul_rn(rintf(__fdiv_rn(p0, step)), step);
          float pq1 = __fmul_rn(rintf(__fdiv_rn(p1, step)), step);
          netsum[o][z*2+kp].x = __fadd_rn(netsum[o][z*2+kp].x, __fsub_rn(pq0, dqv[z]));
          netsum[o][z*2+kp].y = __fadd_rn(netsum[o][z*2+kp].y, __fsub_rn(pq1, dqv[z]));
        }
  }
  float xmax = (float)readSlot(xmax_slot);
  float wmax = (float)readSlot(wmax_slot);
  float A = __fdiv_rn(xmax, 7.0f);
  float B = __fdiv_rn(__fmul_rn(2.0f, wmax), 13.5f);
#pragma unroll
  for (int o = 0; o < OTILE; ++o){
    float tot = 0.0f;
#pragma unroll
    for (int z = 0; z < 3; ++z)
#pragma unroll
      for (int k = 0; k < 4; ++k){
        f32x2 ns = netsum[o][z*2 + (k >> 1)];
        float nv = (k & 1) ? ns.y : ns.x;
        tot = __fadd_rn(tot, __fmul_rn(nv, (float)(1 << (z + k))));
      }
    float outv = __fadd_rn(__fmul_rn(__fmul_rn(tot, A), B), bias[o0+o]);
    outT[(size_t)(o0+o)*TOK + t] = outv;
  }
}

__global__ void gelu_absmax_k(const float* m1, int n, float* x2, unsigned long long* xmax_slot){
  __shared__ double red[256];
  double m = 0.0;
  for (int i = blockIdx.x*256 + threadIdx.x; i < n; i += gridDim.x*256){
    float v = m1[i];
    float t1 = __fdiv_rn(v, 1.4142135623730951f);
    float e = xla_erf_f32(t1);
    float s = __fadd_rn(e, 1.0f);
    float g = __fdiv_rn(__fmul_rn(v, s), 2.0f);
    x2[i] = g;
    double a = fabs((double)g); if (a > m) m = a;
  }
  blockMaxAtomic(m, xmax_slot, red);
}

// ---------------- host launch ----------------
extern "C" void kernel_launch(void* const* d_in, const int* in_sizes, int n_in,
                              void* d_out, int out_size, void* d_ws, size_t ws_size,
                              hipStream_t stream){
  if (ws_size < WS_NEEDED) return;
  const bool big = (ws_size >= WS_BIG);   // partial-cache path fits?

  const float* x      = (const float*)d_in[0];
  const float* in_w   = (const float*)d_in[1];
  const float* in_b   = (const float*)d_in[2];
  const float* out_w  = (const float*)d_in[3];
  const float* out_b  = (const float*)d_in[4];
  const float* ln1_g  = (const float*)d_in[5];
  const float* ln1_b  = (const float*)d_in[6];
  const float* W1     = (const float*)d_in[7];
  const float* b1     = (const float*)d_in[8];
  const float* W2     = (const float*)d_in[9];
  const float* b2     = (const float*)d_in[10];
  const float* ln2_g  = (const float*)d_in[11];
  const float* ln2_b  = (const float*)d_in[12];

  char* ws = (char*)d_ws;
  unsigned long long* scal = (unsigned long long*)(ws + OFF_SCAL);
  float* qkv    = (float*)(ws + OFF_QKV);
  float* scores = (float*)(ws + OFF_SCORES);
  float* ctx    = (float*)(ws + OFF_CTX);
  float* h1pre  = (float*)(ws + OFF_H1PRE);
  float* h1     = (float*)(ws + OFF_H1);
  float* m1     = (float*)(ws + OFF_M1);     // [MLPD][TOK]
  float* x2     = (float*)(ws + OFF_X2);     // [MLPD][TOK]
  float* m2     = (float*)(ws + OFF_M2);     // [EMB][TOK]
  float* dq1    = (float*)(ws + OFF_DQ1);
  float* dq2    = (float*)(ws + OFF_DQ2);
  int*   sumxb1 = (int*)(ws + OFF_SUMXB1);
  int*   sumxb2 = (int*)(ws + OFF_SUMXB2);
  unsigned char* wdec1 = (unsigned char*)(ws + OFF_WDEC1);
  unsigned char* wdec2 = (unsigned char*)(ws + OFF_WDEC2);
  unsigned char* xqt1 = (unsigned char*)(ws + OFF_XQT1);
  unsigned char* xqt2 = (unsigned char*)(ws + OFF_XQT2);
  float* cond1 = (float*)(ws + OFF_COND1);
  float* cond2 = (float*)(ws + OFF_COND2);
  float* part  = (float*)(ws + OFF_PART);

  hipMemsetAsync(scal, 0, 64, stream);

  absmax_f32_k<<<1024,256,0,stream>>>(W1, MLPD*EMB, scal+0);
  absmax_f32_k<<<1024,256,0,stream>>>(W2, EMB*MLPD, scal+1);
  wdec_gen_k<<<9216,256,0,stream>>>(W1, MLPD*EMB, scal+0, wdec1);
  wdec_gen_k<<<9216,256,0,stream>>>(W2, EMB*MLPD, scal+1, wdec2);
  cond_gen_k<<<36864,256,0,stream>>>(0u, 1u, wdec1, 9437184u, cond1);
  cond_gen_k<<<36864,256,0,stream>>>(0u, 2u, wdec2, 9437184u, cond2);

  // attention (f32, XLA-faithful)
  gemm8_k<<<dim3(9,64),256,0,stream>>>(x, in_w, in_b, nullptr, qkv, QKVD, EMB);
  attn_scores_k<<<dim3(24,8),256,0,stream>>>(qkv, scores);
  softmax_rows_k<<<24,256,0,stream>>>(scores);
  attn_ctx_k<<<768,256,0,stream>>>(scores, qkv, ctx);
  gemm8_k<<<dim3(3,64),256,0,stream>>>(ctx, out_w, out_b, x, h1pre, EMB, EMB);
  ln_rows_k<<<2,256,0,stream>>>(h1pre, ln1_g, ln1_b, h1);

  // qlinear 1 (768 -> 3072)
  absmax_f32_k<<<1024,256,0,stream>>>(h1, TOK*EMB, scal+2);
  quantx_k<<<(TOK*EMB+255)/256,256,0,stream>>>(h1, scal+2, EMB, xqt1);
  sumxb_k<<<(TOK*6+255)/256,256,0,stream>>>(xqt1, 6, sumxb1, scal+4);
  dummyq_k<<<(TOK*6*3+255)/256,256,0,stream>>>(sumxb1, 6, scal+4, dq1);
  if (big){
    qlin_k<4,false,3,true><<<dim3(MLPD/4,2,2),256,0,stream>>>(xqt1, cond1, nullptr, nullptr,
        EMB, 6, MLPD, scal+3, scal+2, scal+0, nullptr, part);
    qlin2c_k<1><<<dim3(MLPD,2),256,0,stream>>>(part, dq1, b1, MLPD, 6,
        scal+3, scal+2, scal+0, m1);
  } else {
    qlin_k<4,false,3,false><<<dim3(MLPD/4,2,2),256,0,stream>>>(xqt1, cond1, nullptr, nullptr,
        EMB, 6, MLPD, scal+3, scal+2, scal+0, nullptr, nullptr);
    qlin_k<4,true,1,false><<<dim3(MLPD/4,2),256,0,stream>>>(xqt1, cond1, dq1, b1,
        EMB, 6, MLPD, scal+3, scal+2, scal+0, m1, nullptr);
  }

  // gelu + qlinear 2 (3072 -> 768)
  gelu_absmax_k<<<6144,256,0,stream>>>(m1, TOK*MLPD, x2, scal+5);
  quantxT_k<<<(TOK*MLPD+255)/256,256,0,stream>>>(x2, scal+5, MLPD, xqt2);
  sumxb_k<<<(TOK*24+255)/256,256,0,stream>>>(xqt2, 24, sumxb2, scal+7);
  dummyq_k<<<(TOK*24*3+255)/256,256,0,stream>>>(sumxb2, 24, scal+7, dq2);
  if (big){
    qlin_k<4,false,6,true><<<dim3(EMB/4,2,4),256,0,stream>>>(xqt2, cond2, nullptr, nullptr,
        MLPD, 24, EMB, scal+6, scal+5, scal+1, nullptr, part);
    qlin2c_k<1><<<dim3(EMB,2),256,0,stream>>>(part, dq2, b2, EMB, 24,
        scal+6, scal+5, scal+1, m2);
  } else {
    qlin_k<4,false,6,false><<<dim3(EMB/4,2,4),256,0,stream>>>(xqt2, cond2, nullptr, nullptr,
        MLPD, 24, EMB, scal+6, scal+5, scal+1, nullptr, nullptr);
    qlin_k<2,true,1,false><<<dim3(EMB/2,2),256,0,stream>>>(xqt2, cond2, dq2, b2,
        MLPD, 24, EMB, scal+6, scal+5, scal+1, m2, nullptr);
  }

  // final residual + layernorm -> f32 out
  final_ln_rows_k<<<2,256,0,stream>>>(h1, m2, ln2_g, ln2_b, (float*)d_out);
}

// Round 11
// 2810.560 us; speedup vs baseline: 1.0789x; 1.0789x over previous
//
#include <hip/hip_runtime.h>
#include <math.h>
#include <stdint.h>

// ---------------- problem constants ----------------
#define TOK   512
#define EMB   768
#define QKVD  2304
#define NHEAD 12
#define HD    64
#define MLPD  3072
#define SUBA  128

// ---------------- ws layout (bytes) ----------------
#define OFF_SCAL     0ull
#define OFF_QKV      256ull
#define OFF_SCORES   (OFF_QKV    + 4718592ull)
#define OFF_CTX      (OFF_SCORES + 6291456ull)
#define OFF_H1PRE    (OFF_CTX    + 1572864ull)
#define OFF_H1       (OFF_H1PRE  + 1572864ull)
#define OFF_M1       (OFF_H1     + 1572864ull)
#define OFF_X2       (OFF_M1     + 6291456ull)
#define OFF_M2       (OFF_X2     + 6291456ull)
#define OFF_DQ1      (OFF_M2     + 1572864ull)
#define OFF_DQ2      (OFF_DQ1    + 36864ull)
#define OFF_SUMXB1   (OFF_DQ2    + 147456ull)
#define OFF_SUMXB2   (OFF_SUMXB1 + 36864ull)
#define OFF_WDEC1    (OFF_SUMXB2 + 147456ull)
#define OFF_WDEC2    (OFF_WDEC1  + 2359296ull)
#define OFF_XQT1     (OFF_WDEC2  + 2359296ull)
#define OFF_XQT2     (OFF_XQT1   + 393216ull)
#define OFF_COND1    (OFF_XQT2   + 1572864ull)
#define OFF_COND2    (OFF_COND1  + 37748736ull)
#define WS_NEEDED    (OFF_COND2  + 37748736ull)

// scalar slots: 0 wmax1, 1 wmax2, 2 xmax1, 3 ymax1, 4 dmax1, 5 xmax2, 6 ymax2, 7 dmax2

typedef float f32x2 __attribute__((ext_vector_type(2)));

// packed 2xf32 fma as two INDEPENDENT IEEE f32 fmas.
// NUMERICS+PERF LEDGER:
//  r4-r6: builtin form, absmax 0.0078125.
//  r7: restructure (+asm pkfma) -> absmax 0.09375; r8 reverted asm, absmax stayed
//      0.09375 => deviation belongs to the (unlocated) restructure, not the asm.
//  r10: asm re-applied in isolation -> absmax unchanged 0.09375 (asm exonerated on
//      numerics) but qlin 538->555us (asm adds reg moves) => builtin is ALSO the
//      faster form. KEEP BUILTIN.
__device__ __forceinline__ f32x2 pkfma(f32x2 a, f32x2 b, f32x2 c){
#if __has_builtin(__builtin_elementwise_fma)
  return __builtin_elementwise_fma(a, b, c);
#else
  f32x2 r; r.x = fmaf(a.x, b.x, c.x); r.y = fmaf(a.y, b.y, c.y); return r;
#endif
}

// ---------------- helpers ----------------
__device__ __forceinline__ void blockMaxAtomic(double v, unsigned long long* slot, double* red){
  int tid = threadIdx.x;
  red[tid] = v; __syncthreads();
  for (int st = 128; st > 0; st >>= 1){
    if (tid < st){ double o = red[tid+st]; if (o > red[tid]) red[tid] = o; }
    __syncthreads();
  }
  if (tid == 0) atomicMax(slot, (unsigned long long)__double_as_longlong(red[0]));
}

__device__ __forceinline__ double readSlot(const unsigned long long* s){
  return __longlong_as_double((long long)(*s));
}

// ---------------- XLA CPU f32 exp (Eigen pexp_float, FMA path) ----------------
__device__ __forceinline__ float xla_exp_f32(float _x){
  float x = fminf(_x, 88.3762626647950f);
  x = fmaxf(x, -88.3762626647949f);
  float m = floorf(fmaf(x, 1.44269504088896341f, 0.5f));
  float r = fmaf(m, -0.6931471805599453f, x);
  float r2 = __fmul_rn(r, r);
  float r3 = __fmul_rn(r2, r);
  float y  = fmaf(1.9875691500e-4f, r, 1.3981999507e-3f);
  float y1 = fmaf(4.1665795894e-2f, r, 1.6666665459e-1f);
  float y2 = __fadd_rn(r, 1.0f);
  y  = fmaf(y, r, 8.3334519073e-3f);
  y1 = fmaf(y1, r, 5.0000001201e-1f);
  y  = fmaf(y, r3, y1);
  y  = fmaf(y, r2, y2);
  int mi = (int)m;
  float two_m = __uint_as_float((unsigned)((mi + 127) << 23));
  float res = __fmul_rn(y, two_m);
  return fmaxf(res, _x);
}

// ---------------- XLA CPU f32 erf (Eigen generic_fast_erf_float) ----------------
__device__ __forceinline__ float xla_erf_f32(float v){
  float x = fmaxf(fminf(v, 4.0f), -4.0f);
  float x2 = __fmul_rn(x, x);
  float p = fmaf(x2, -2.72614225801306e-10f, 2.77068142495902e-08f);
  p = fmaf(x2, p, -2.10102402082508e-06f);
  p = fmaf(x2, p, -5.69250639462346e-05f);
  p = fmaf(x2, p, -7.34990630326855e-04f);
  p = fmaf(x2, p, -2.95459980854025e-03f);
  p = fmaf(x2, p, -1.60960333262415e-02f);
  p = __fmul_rn(x, p);
  float q = fmaf(x2, -1.45660718464996e-05f, -2.13374055278905e-04f);
  q = fmaf(x2, q, -1.68282697438203e-03f);
  q = fmaf(x2, q, -7.37332916720468e-03f);
  q = fmaf(x2, q, -1.42647390514189e-02f);
  return __fdiv_rn(p, q);
}

// ---------------- threefry2x32 (JAX-exact) ----------------
__device__ __forceinline__ uint32_t rotl32(uint32_t x, int r){ return (x << r) | (x >> (32 - r)); }

__device__ __forceinline__ void threefry2x32(uint32_t k0, uint32_t k1,
                                             uint32_t x0, uint32_t x1,
                                             uint32_t& o0, uint32_t& o1){
  uint32_t ks2 = k0 ^ k1 ^ 0x1BD11BDAu;
  x0 += k0; x1 += k1;
#define TF_R(r) { x0 += x1; x1 = rotl32(x1, r); x1 ^= x0; }
  TF_R(13) TF_R(15) TF_R(26) TF_R(6)
  x0 += k1; x1 += ks2 + 1u;
  TF_R(17) TF_R(29) TF_R(16) TF_R(24)
  x0 += ks2; x1 += k0 + 2u;
  TF_R(13) TF_R(15) TF_R(26) TF_R(6)
  x0 += k0; x1 += k1 + 3u;
  TF_R(17) TF_R(29) TF_R(16) TF_R(24)
  x0 += k1; x1 += ks2 + 4u;
  TF_R(13) TF_R(15) TF_R(26) TF_R(6)
  x0 += ks2; x1 += k0 + 5u;
#undef TF_R
  o0 = x0; o1 = x1;
}

__device__ float bits_to_noise(uint32_t bits){
  uint32_t fb = (bits >> 9) | 0x3f800000u;
  float f = __uint_as_float(fb);
  f = __fadd_rn(f, -1.0f);
  const float lo = -0.99999994f;
  float u = __fadd_rn(__fmul_rn(f, 2.0f), lo);
  u = fmaxf(lo, u);
  float x  = u;
  float xx = __fmul_rn(x, x);
  float nx = -xx;
  float l1p;
  if (fabsf(nx) < 1e-4f){
    l1p = __fmul_rn(__fadd_rn(__fmul_rn(-0.5f, nx), 1.0f), nx);
  } else {
    float u1 = __fadd_rn(nx, 1.0f);
    l1p = (float)log((double)u1);
  }
  float w = -l1p;
  float p;
  if (w < 5.0f){
    w = __fadd_rn(w, -2.5f);
    p = 2.81022636e-08f;
    p = __fadd_rn(3.43273939e-07f, __fmul_rn(p, w));
    p = __fadd_rn(-3.5233877e-06f,  __fmul_rn(p, w));
    p = __fadd_rn(-4.39150654e-06f, __fmul_rn(p, w));
    p = __fadd_rn(0.00021858087f,   __fmul_rn(p, w));
    p = __fadd_rn(-0.00125372503f,  __fmul_rn(p, w));
    p = __fadd_rn(-0.00417768164f,  __fmul_rn(p, w));
    p = __fadd_rn(0.246640727f,     __fmul_rn(p, w));
    p = __fadd_rn(1.50140941f,      __fmul_rn(p, w));
  } else {
    float sw = __fsqrt_rn(w);
    w = __fadd_rn(sw, -3.0f);
    p = -0.000200214257f;
    p = __fadd_rn(0.000100950558f, __fmul_rn(p, w));
    p = __fadd_rn(0.00134934322f,  __fmul_rn(p, w));
    p = __fadd_rn(-0.00367342844f, __fmul_rn(p, w));
    p = __fadd_rn(0.00573950773f,  __fmul_rn(p, w));
    p = __fadd_rn(-0.0076224613f,  __fmul_rn(p, w));
    p = __fadd_rn(0.00943887047f,  __fmul_rn(p, w));
    p = __fadd_rn(1.00167406f,     __fmul_rn(p, w));
    p = __fadd_rn(2.83297682f,     __fmul_rn(p, w));
  }
  float ei  = __fmul_rn(p, x);
  float nrm = __fmul_rn(1.41421354f, ei);
  return __fmul_rn(0.02f, nrm);
}

// ---------------- reductions ----------------
__global__ void absmax_f32_k(const float* p, int n, unsigned long long* slot){
  __shared__ double red[256];
  double m = 0.0;
  for (int i = blockIdx.x*256 + threadIdx.x; i < n; i += gridDim.x*256){
    double v = fabs((double)p[i]); if (v > m) m = v;
  }
  blockMaxAtomic(m, slot, red);
}

// ---------------- weight preprocessing ----------------
__global__ void wdec_gen_k(const float* W, int nW, const unsigned long long* wmax_slot,
                           unsigned char* Wdec){
  int i = blockIdx.x*256 + threadIdx.x;
  if (i >= nW) return;
  float wmax = (float)readSlot(wmax_slot);
  float d = __fdiv_rn(W[i], wmax);
  d = __fadd_rn(d, 1.0f);
  d = __fmul_rn(d, 0.5f);
  d = __fmul_rn(d, 15.0f);
  Wdec[i] = (unsigned char)(int)rintf(d);
}

// cond[j], j=i*4+k: partitionable threefry (block (0,j), xor) -> noise -> conductance
__global__ void cond_gen_k(uint32_t k0, uint32_t k1, const unsigned char* Wdec,
                           unsigned int n4, float* cond){
  unsigned int j = blockIdx.x*256u + threadIdx.x;
  if (j >= n4) return;
  uint32_t o0, o1;
  threefry2x32(k0, k1, 0u, j, o0, o1);
  float nz = bits_to_noise(o0 ^ o1);
  float bit = (float)((Wdec[j >> 2] >> (j & 3)) & 1);
  cond[j] = __fmul_rn(__fadd_rn(__fmul_rn(bit, 0.9f), 0.1f), __fadd_rn(1.0f, nz));
}

// ---------------- fused row-major GEMM ----------------
#define KTILE 32
__global__ __launch_bounds__(256) void gemm8_k(const float* src, const float* w, const float* bias,
                                               const float* resid, float* out, int N, int K){
  __shared__ float xt[EMB*8];
  __shared__ float wl[256*(KTILE+1)];
  const int tid = threadIdx.x;
  const int j  = blockIdx.x*256 + tid;
  const int t0 = blockIdx.y*8;
  for (int v = tid; v < K*8; v += 256){
    int e = v >> 3, tt = v & 7;
    xt[v] = src[(size_t)(t0+tt)*K + e];
  }
  f32x2 acc[4] = {{0.f,0.f},{0.f,0.f},{0.f,0.f},{0.f,0.f}};
  const int ntile = K / KTILE;
  for (int et = 0; et < ntile; ++et){
    __syncthreads();
    for (int v = tid; v < 256*KTILE; v += 256){
      int r = v >> 5, cc = v & 31;
      wl[r*(KTILE+1) + cc] = w[(size_t)(blockIdx.x*256 + r)*K + et*KTILE + cc];
    }
    __syncthreads();
    for (int ee = 0; ee < KTILE; ++ee){
      float wv = wl[tid*(KTILE+1) + ee];
      f32x2 wv2 = {wv, wv};
      const f32x2* xp = (const f32x2*)&xt[(et*KTILE + ee)*8];
#pragma unroll
      for (int q = 0; q < 4; ++q) acc[q] = pkfma(xp[q], wv2, acc[q]);
    }
  }
  float bv = bias[j];
#pragma unroll
  for (int q = 0; q < 4; ++q){
    float a0 = __fadd_rn(acc[q].x, bv);
    float a1 = __fadd_rn(acc[q].y, bv);
    size_t ta = (size_t)(t0 + q*2), tb = ta + 1;
    if (resid){
      out[ta*N + j] = __fadd_rn(resid[ta*N + j], a0);
      out[tb*N + j] = __fadd_rn(resid[tb*N + j], a1);
    } else {
      out[ta*N + j] = a0;
      out[tb*N + j] = a1;
    }
  }
}

// ---------------- attention ----------------
__global__ __launch_bounds__(256) void attn_scores_k(const float* qkv, float* sc){
  __shared__ float kt[64][34];
  int nh = blockIdx.x;
  int n  = nh / NHEAD, h = nh % NHEAD;
  int m0 = blockIdx.y * 32;
  int l  = threadIdx.x;
  for (int v = threadIdx.x; v < 32*64; v += 256){
    int mm = v >> 6, d = v & 63;
    kt[d][mm] = qkv[(size_t)((m0+mm)*2 + n)*QKVD + EMB + h*HD + d];
  }
  __syncthreads();
  f32x2 acc[16];
#pragma unroll
  for (int i = 0; i < 16; ++i) acc[i] = {0.f,0.f};
  const float* qrow = qkv + (size_t)(l*2 + n)*QKVD + h*HD;
  for (int d = 0; d < HD; ++d){
    float qv = qrow[d];
    f32x2 q2 = {qv, qv};
    const f32x2* kp = (const f32x2*)&kt[d][0];
#pragma unroll
    for (int i = 0; i < 16; ++i) acc[i] = pkfma(q2, kp[i], acc[i]);
  }
  float* srow = sc + ((size_t)nh*256 + l)*256 + m0;
#pragma unroll
  for (int i = 0; i < 16; ++i){
    srow[2*i]   = __fdiv_rn(acc[i].x, 8.0f);
    srow[2*i+1] = __fdiv_rn(acc[i].y, 8.0f);
  }
}

__global__ void softmax_rows_k(float* sc){
  int row = blockIdx.x*256 + threadIdx.x;
  if (row >= 24*256) return;
  float* p = sc + (size_t)row*256;
  float mx = p[0];
  for (int m = 1; m < 256; ++m) mx = fmaxf(mx, p[m]);
  for (int m = 0; m < 256; ++m) p[m] = xla_exp_f32(__fsub_rn(p[m], mx));
  float s = 0.0f;
  for (int m = 0; m < 256; ++m) s = __fadd_rn(s, p[m]);
  for (int m = 0; m < 256; ++m) p[m] = __fdiv_rn(p[m], s);
}

__global__ void attn_ctx_k(const float* sc, const float* qkv, float* ctx){
  int idx = blockIdx.x*256 + threadIdx.x;
  int t = idx / 384, i2 = idx % 384;
  int i = i2*2;
  int l = t >> 1, n = t & 1, h = i >> 6;
  const float* arow = sc + ((size_t)(n*NHEAD + h)*256 + l)*256;
  f32x2 acc = {0.f,0.f};
  for (int m = 0; m < 256; ++m){
    float av = arow[m];
    f32x2 a2 = {av, av};
    f32x2 v2 = *(const f32x2*)&qkv[(size_t)(m*2 + n)*QKVD + 1536 + i];
    acc = pkfma(a2, v2, acc);
  }
  ctx[(size_t)t*EMB + i]     = acc.x;
  ctx[(size_t)t*EMB + i + 1] = acc.y;
}

__global__ void ln_rows_k(const float* in, const float* g, const float* b, float* out){
  int t = blockIdx.x*256 + threadIdx.x;
  if (t >= TOK) return;
  const float* p = in + (size_t)t*EMB;
  float s = 0.0f;
  for (int e = 0; e < EMB; ++e) s = __fadd_rn(s, p[e]);
  float mu = __fdiv_rn(s, 768.0f);
  float s2 = 0.0f;
  for (int e = 0; e < EMB; ++e){
    float d = __fsub_rn(p[e], mu);
    s2 = __fadd_rn(s2, __fmul_rn(d, d));
  }
  float var = __fdiv_rn(s2, 768.0f);
  float rs = __fdiv_rn(1.0f, __fsqrt_rn(__fadd_rn(var, 1e-5f)));
  for (int e = 0; e < EMB; ++e){
    float d = __fsub_rn(p[e], mu);
    out[(size_t)t*EMB + e] = __fadd_rn(__fmul_rn(__fmul_rn(d, rs), g[e]), b[e]);
  }
}

__global__ void final_ln_rows_k(const float* h1, const float* m2T, const float* g, const float* b, float* out){
  int t = blockIdx.x*256 + threadIdx.x;
  if (t >= TOK) return;
  const float* p = h1 + (size_t)t*EMB;
  float s = 0.0f;
  for (int e = 0; e < EMB; ++e) s = __fadd_rn(s, __fadd_rn(p[e], m2T[(size_t)e*TOK + t]));
  float mu = __fdiv_rn(s, 768.0f);
  float s2 = 0.0f;
  for (int e = 0; e < EMB; ++e){
    float d = __fsub_rn(__fadd_rn(p[e], m2T[(size_t)e*TOK + t]), mu);
    s2 = __fadd_rn(s2, __fmul_rn(d, d));
  }
  float var = __fdiv_rn(s2, 768.0f);
  float rs = __fdiv_rn(1.0f, __fsqrt_rn(__fadd_rn(var, 1e-5f)));
  for (int e = 0; e < EMB; ++e){
    float d = __fsub_rn(__fadd_rn(p[e], m2T[(size_t)e*TOK + t]), mu);
    out[(size_t)t*EMB + e] = __fadd_rn(__fmul_rn(__fmul_rn(d, rs), g[e]), b[e]);
  }
}

// ---------------- qlinear (strict f32) ----------------
// XqT2 layout: [c][t][s], one byte per s: three 2-bit signed fields (s0,s1,s2).
__device__ __forceinline__ unsigned char encode_q(int q){
  int a = q < 0 ? -q : q;
  int s0 = a & 1, s1 = (a >> 1) & 1, s2 = (a >> 2) & 1;
  if (q < 0){ s0 = -s0; s1 = -s1; s2 = -s2; }
  return (unsigned char)((s0 & 3) | ((s1 & 3) << 2) | ((s2 & 3) << 4));
}

__global__ void quantx_k(const float* val /*[t][Fin]*/, const unsigned long long* xmax_slot,
                         int Fin, unsigned char* XqT2){
  int idx = blockIdx.x*256 + threadIdx.x;
  if (idx >= TOK*Fin) return;
  int t = idx / Fin, e = idx % Fin;
  float xmax = (float)readSlot(xmax_slot);
  float u = __fmul_rn(__fdiv_rn(val[idx], xmax), 7.0f);
  XqT2[((size_t)(e >> 7)*TOK + t)*SUBA + (e & 127)] = encode_q((int)rintf(u));
}

__global__ void quantxT_k(const float* valT /*[i][t]*/, const unsigned long long* xmax_slot,
                          int Fin, unsigned char* XqT2){
  int idx = blockIdx.x*256 + threadIdx.x;
  if (idx >= TOK*Fin) return;
  int i = idx / TOK, t = idx % TOK;
  float xmax = (float)readSlot(xmax_slot);
  float u = __fmul_rn(__fdiv_rn(valT[idx], xmax), 7.0f);
  XqT2[((size_t)(i >> 7)*TOK + t)*SUBA + (i & 127)] = encode_q((int)rintf(u));
}

__global__ void sumxb_k(const unsigned char* XqT2, int NC, int* sumxb, unsigned long long* dmax_slot){
  int idx = blockIdx.x*256 + threadIdx.x;
  if (idx >= TOK*NC) return;
  int t = idx / NC, c = idx % NC;
  const unsigned char* row = XqT2 + ((size_t)c*TOK + t)*SUBA;
  int n0 = 0, n1 = 0, n2 = 0;
  for (int s = 0; s < SUBA; ++s){
    int e = (int)row[s];
    n0 += ((int)((unsigned)e << 30)) >> 30;
    n1 += ((int)((unsigned)e << 28)) >> 30;
    n2 += ((int)((unsigned)e << 26)) >> 30;
  }
  sumxb[idx*3 + 0] = n0; sumxb[idx*3 + 1] = n1; sumxb[idx*3 + 2] = n2;
  float d0 = fabsf(__fmul_rn(0.55f, (float)n0));
  float d1 = fabsf(__fmul_rn(0.55f, (float)n1));
  float d2 = fabsf(__fmul_rn(0.55f, (float)n2));
  float m = fmaxf(d0, fmaxf(d1, d2));
  atomicMax(dmax_slot, (unsigned long long)__double_as_longlong((double)m));
}

// dqT layout: [c][z][t]
__global__ void dummyq_k(const int* sumxb, int NC, const unsigned long long* dmax_slot, float* dqT){
  int idx = blockIdx.x*256 + threadIdx.x;
  if (idx >= TOK*NC*3) return;
  int t = idx / (NC*3);
  int r = idx % (NC*3);
  int c = r / 3, z = r % 3;
  float dmax = (float)readSlot(dmax_slot);
  float step = __fdiv_rn(dmax, 31.0f);
  if (!(step > 0.0f)) step = 1.0f;
  float P = __fmul_rn(0.55f, (float)sumxb[idx]);
  dqT[((size_t)c*3 + z)*TOK + t] = __fmul_rn(rintf(__fdiv_rn(P, step)), step);
}

// unified crossbar pass. P2=false: ymax (c-chunked via blockIdx.z). P2=true: output.
// OTILE=2 everywhere (r11): VGPR ~56 (<64 bucket) + 4KB LDS -> ~2x occupancy vs
// OTILE=4 (92 VGPR, 16KB). Value-identical: per-(t,o) chains unchanged.
// Exactness: per (t,o,c,z,k) chain s=0..127 ascending; netsum per (z,k) c-ascending;
// tot z-major 12-term — identical to rounds 7-10 validated semantics.
template<int OTILE, bool P2, int CCHUNK>
__global__ __launch_bounds__(256) void qlin_k(const unsigned char* XqT2, const float* cond_g,
                                              const float* dqT, const float* bias,
                                              int Fin, int NC,
                                              unsigned long long* ymax_slot,
                                              const unsigned long long* xmax_slot,
                                              const unsigned long long* wmax_slot,
                                              float* outT){
  __shared__ float condL[OTILE*SUBA*4];
  __shared__ double red[P2 ? 1 : 256];
  const int tid = threadIdx.x;
  const int o0 = blockIdx.x*OTILE;
  const int t0 = blockIdx.y*256;
  const int t  = t0 + tid;
  const int c0 = P2 ? 0 : blockIdx.z*CCHUNK;
  const int cEnd = P2 ? NC : (c0 + CCHUNK);

  float step = 1.0f, lmax = 0.0f;
  if (P2){
    float ymax = (float)readSlot(ymax_slot);
    step = __fdiv_rn(ymax, 31.0f);
    if (!(step > 0.0f)) step = 1.0f;
  }

  f32x2 acc[OTILE][6];
  f32x2 netsum[OTILE][6];
  if (P2){
#pragma unroll
    for (int o = 0; o < OTILE; ++o)
#pragma unroll
      for (int r = 0; r < 6; ++r) netsum[o][r] = (f32x2){0.f, 0.f};
  }

  // stage cond for first c
#pragma unroll
  for (int u = 0; u < OTILE/2; ++u){
    int v = tid + u*256, o = v >> 7, r = v & 127;
    ((float4*)condL)[v] = ((const float4*)cond_g)[(size_t)(o0+o)*Fin + (size_t)c0*SUBA + r];
  }
  __syncthreads();

  // prime xq: first 8 dwords of first c's row
  const uint32_t* xrow = (const uint32_t*)(XqT2 + ((size_t)c0*TOK + t)*SUBA);
  uint32_t xg[8];
#pragma unroll
  for (int u = 0; u < 8; ++u) xg[u] = xrow[u];

  for (int c = c0; c < cEnd; ++c){
    const bool haveNextC = (c + 1 < cEnd);
    const uint32_t* xrow_next = haveNextC
      ? (const uint32_t*)(XqT2 + ((size_t)(c+1)*TOK + t)*SUBA) : xrow;

    // prefetch next-c cond into registers (hidden under the 128-s compute)
    float4 pf[OTILE/2];
    if (haveNextC){
#pragma unroll
      for (int u = 0; u < OTILE/2; ++u){
        int v = tid + u*256, o = v >> 7, r = v & 127;
        pf[u] = ((const float4*)cond_g)[(size_t)(o0+o)*Fin + (size_t)(c+1)*SUBA + r];
      }
    }

#pragma unroll
    for (int o = 0; o < OTILE; ++o)
#pragma unroll
      for (int r = 0; r < 6; ++r) acc[o][r] = (f32x2){0.f, 0.f};

    for (int g = 0; g < 4; ++g){            // 32 s per group; rolling prefetch incl. next c
      uint32_t xn[8];
      const uint32_t* nsrc = (g < 3) ? (xrow + (g+1)*8) : xrow_next;
#pragma unroll
      for (int u = 0; u < 8; ++u) xn[u] = nsrc[u];
      const float* condG = condL + g*32*4;
#pragma unroll
      for (int u = 0; u < 8; ++u){
        uint32_t w = xg[u];
#pragma unroll
        for (int bb = 0; bb < 4; ++bb){
          int sl = u*4 + bb;                 // s within group (compile-time)
          int base = bb*8;
          int b0i = ((int)(w << (30 - base))) >> 30;
          int b1i = ((int)(w << (28 - base))) >> 30;
          int b2i = ((int)(w << (26 - base))) >> 30;
          float f0 = (float)b0i, f1 = (float)b1i, f2 = (float)b2i;
          f32x2 b0 = {f0, f0}, b1 = {f1, f1}, b2 = {f2, f2};
#pragma unroll
          for (int o = 0; o < OTILE; ++o){
            const f32x2* cp = (const f32x2*)&condG[(o*SUBA + sl)*4];
            f32x2 c01 = cp[0], c23 = cp[1];
            acc[o][0] = pkfma(b0, c01, acc[o][0]);
            acc[o][1] = pkfma(b0, c23, acc[o][1]);
            acc[o][2] = pkfma(b1, c01, acc[o][2]);
            acc[o][3] = pkfma(b1, c23, acc[o][3]);
            acc[o][4] = pkfma(b2, c01, acc[o][4]);
            acc[o][5] = pkfma(b2, c23, acc[o][5]);
          }
        }
      }
#pragma unroll
      for (int u = 0; u < 8; ++u) xg[u] = xn[u];
    }
    xrow = xrow_next;

    if (P2){
      float dqv[3];
#pragma unroll
      for (int z = 0; z < 3; ++z) dqv[z] = dqT[((size_t)c*3 + z)*TOK + t];
#pragma unroll
      for (int o = 0; o < OTILE; ++o)
#pragma unroll
        for (int z = 0; z < 3; ++z)
#pragma unroll
          for (int kp = 0; kp < 2; ++kp){
            f32x2 av = acc[o][z*2 + kp];
            float pq0 = __fmul_rn(rintf(__fdiv_rn(av.x, step)), step);
            float pq1 = __fmul_rn(rintf(__fdiv_rn(av.y, step)), step);
            netsum[o][z*2+kp].x = __fadd_rn(netsum[o][z*2+kp].x, __fsub_rn(pq0, dqv[z]));
            netsum[o][z*2+kp].y = __fadd_rn(netsum[o][z*2+kp].y, __fsub_rn(pq1, dqv[z]));
          }
    } else {
#pragma unroll
      for (int o = 0; o < OTILE; ++o)
#pragma unroll
        for (int r = 0; r < 6; ++r){
          lmax = fmaxf(lmax, fabsf(acc[o][r].x));
          lmax = fmaxf(lmax, fabsf(acc[o][r].y));
        }
    }

    __syncthreads();
    if (haveNextC){
#pragma unroll
      for (int u = 0; u < OTILE/2; ++u)
        ((float4*)condL)[tid + u*256] = pf[u];
      __syncthreads();
    }
  }

  if (P2){
    float xmax = (float)readSlot(xmax_slot);
    float wmax = (float)readSlot(wmax_slot);
    float A = __fdiv_rn(xmax, 7.0f);
    float B = __fdiv_rn(__fmul_rn(2.0f, wmax), 13.5f);
#pragma unroll
    for (int o = 0; o < OTILE; ++o){
      float tot = 0.0f;
#pragma unroll
      for (int z = 0; z < 3; ++z)
#pragma unroll
        for (int k = 0; k < 4; ++k){
          f32x2 ns = netsum[o][z*2 + (k >> 1)];
          float nv = (k & 1) ? ns.y : ns.x;
          tot = __fadd_rn(tot, __fmul_rn(nv, (float)(1 << (z + k))));
        }
      float outv = __fadd_rn(__fmul_rn(__fmul_rn(tot, A), B), bias[o0+o]);
      outT[(size_t)(o0+o)*TOK + t] = outv;
    }
  } else {
    blockMaxAtomic((double)lmax, ymax_slot, red);
  }
}

__global__ void gelu_absmax_k(const float* m1, int n, float* x2, unsigned long long* xmax_slot){
  __shared__ double red[256];
  double m = 0.0;
  for (int i = blockIdx.x*256 + threadIdx.x; i < n; i += gridDim.x*256){
    float v = m1[i];
    float t1 = __fdiv_rn(v, 1.4142135623730951f);
    float e = xla_erf_f32(t1);
    float s = __fadd_rn(e, 1.0f);
    float g = __fdiv_rn(__fmul_rn(v, s), 2.0f);
    x2[i] = g;
    double a = fabs((double)g); if (a > m) m = a;
  }
  blockMaxAtomic(m, xmax_slot, red);
}

// ---------------- host launch ----------------
extern "C" void kernel_launch(void* const* d_in, const int* in_sizes, int n_in,
                              void* d_out, int out_size, void* d_ws, size_t ws_size,
                              hipStream_t stream){
  if (ws_size < WS_NEEDED) return;
  const float* x      = (const float*)d_in[0];
  const float* in_w   = (const float*)d_in[1];
  const float* in_b   = (const float*)d_in[2];
  const float* out_w  = (const float*)d_in[3];
  const float* out_b  = (const float*)d_in[4];
  const float* ln1_g  = (const float*)d_in[5];
  const float* ln1_b  = (const float*)d_in[6];
  const float* W1     = (const float*)d_in[7];
  const float* b1     = (const float*)d_in[8];
  const float* W2     = (const float*)d_in[9];
  const float* b2     = (const float*)d_in[10];
  const float* ln2_g  = (const float*)d_in[11];
  const float* ln2_b  = (const float*)d_in[12];

  char* ws = (char*)d_ws;
  unsigned long long* scal = (unsigned long long*)(ws + OFF_SCAL);
  float* qkv    = (float*)(ws + OFF_QKV);
  float* scores = (float*)(ws + OFF_SCORES);
  float* ctx    = (float*)(ws + OFF_CTX);
  float* h1pre  = (float*)(ws + OFF_H1PRE);
  float* h1     = (float*)(ws + OFF_H1);
  float* m1     = (float*)(ws + OFF_M1);     // [MLPD][TOK]
  float* x2     = (float*)(ws + OFF_X2);     // [MLPD][TOK]
  float* m2     = (float*)(ws + OFF_M2);     // [EMB][TOK]
  float* dq1    = (float*)(ws + OFF_DQ1);
  float* dq2    = (float*)(ws + OFF_DQ2);
  int*   sumxb1 = (int*)(ws + OFF_SUMXB1);
  int*   sumxb2 = (int*)(ws + OFF_SUMXB2);
  unsigned char* wdec1 = (unsigned char*)(ws + OFF_WDEC1);
  unsigned char* wdec2 = (unsigned char*)(ws + OFF_WDEC2);
  unsigned char* xqt1 = (unsigned char*)(ws + OFF_XQT1);
  unsigned char* xqt2 = (unsigned char*)(ws + OFF_XQT2);
  float* cond1 = (float*)(ws + OFF_COND1);
  float* cond2 = (float*)(ws + OFF_COND2);

  hipMemsetAsync(scal, 0, 64, stream);

  absmax_f32_k<<<1024,256,0,stream>>>(W1, MLPD*EMB, scal+0);
  absmax_f32_k<<<1024,256,0,stream>>>(W2, EMB*MLPD, scal+1);
  wdec_gen_k<<<9216,256,0,stream>>>(W1, MLPD*EMB, scal+0, wdec1);
  wdec_gen_k<<<9216,256,0,stream>>>(W2, EMB*MLPD, scal+1, wdec2);
  cond_gen_k<<<36864,256,0,stream>>>(0u, 1u, wdec1, 9437184u, cond1);
  cond_gen_k<<<36864,256,0,stream>>>(0u, 2u, wdec2, 9437184u, cond2);

  // attention (f32, XLA-faithful)
  gemm8_k<<<dim3(9,64),256,0,stream>>>(x, in_w, in_b, nullptr, qkv, QKVD, EMB);
  attn_scores_k<<<dim3(24,8),256,0,stream>>>(qkv, scores);
  softmax_rows_k<<<24,256,0,stream>>>(scores);
  attn_ctx_k<<<768,256,0,stream>>>(scores, qkv, ctx);
  gemm8_k<<<dim3(3,64),256,0,stream>>>(ctx, out_w, out_b, x, h1pre, EMB, EMB);
  ln_rows_k<<<2,256,0,stream>>>(h1pre, ln1_g, ln1_b, h1);

  // qlinear 1 (768 -> 3072), all OTILE=2 for occupancy
  absmax_f32_k<<<1024,256,0,stream>>>(h1, TOK*EMB, scal+2);
  quantx_k<<<(TOK*EMB+255)/256,256,0,stream>>>(h1, scal+2, EMB, xqt1);
  sumxb_k<<<(TOK*6+255)/256,256,0,stream>>>(xqt1, 6, sumxb1, scal+4);
  dummyq_k<<<(TOK*6*3+255)/256,256,0,stream>>>(sumxb1, 6, scal+4, dq1);
  qlin_k<2,false,3><<<dim3(MLPD/2,2,2),256,0,stream>>>(xqt1, cond1, nullptr, nullptr,
                                                       EMB, 6, scal+3, scal+2, scal+0, nullptr);
  qlin_k<2,true,1><<<dim3(MLPD/2,2),256,0,stream>>>(xqt1, cond1, dq1, b1,
                                                    EMB, 6, scal+3, scal+2, scal+0, m1);

  // gelu + qlinear 2 (3072 -> 768)
  gelu_absmax_k<<<6144,256,0,stream>>>(m1, TOK*MLPD, x2, scal+5);
  quantxT_k<<<(TOK*MLPD+255)/256,256,0,stream>>>(x2, scal+5, MLPD, xqt2);
  sumxb_k<<<(TOK*24+255)/256,256,0,stream>>>(xqt2, 24, sumxb2, scal+7);
  dummyq_k<<<(TOK*24*3+255)/256,256,0,stream>>>(sumxb2, 24, scal+7, dq2);
  qlin_k<2,false,6><<<dim3(EMB/2,2,4),256,0,stream>>>(xqt2, cond2, nullptr, nullptr,
                                                      MLPD, 24, scal+6, scal+5, scal+1, nullptr);
  qlin_k<2,true,1><<<dim3(EMB/2,2),256,0,stream>>>(xqt2, cond2, dq2, b2,
                                                   MLPD, 24, scal+6, scal+5, scal+1, m2);

  // final residual + layernorm -> f32 out
  final_ln_rows_k<<<2,256,0,stream>>>(h1, m2, ln2_g, ln2_b, (float*)d_out);
}